// Round 4
// baseline (316.626 us; speedup 1.0000x reference)
//
#include <hip/hip_runtime.h>

#define N_NODES 50000
#define N_EDGES 800000
#define DIM 128
#define NCLS 40

// chunked CSR build
#define NCHUNK 128
#define CE 6250            // NCHUNK*CE == N_EDGES exactly
#define HALF_N 25088       // nodes per half (2*WHALF)
#define WHALF 12544        // packed u32 words per half (= 49*256)
#define SCAN_B 98          // cscan/scan_final blocks (2 halves * 49)
#define N_PAD 50432        // >= 2*HALF_N padded node arrays

typedef __bf16 bf16x8_t __attribute__((ext_vector_type(8)));
typedef unsigned short us8_t __attribute__((ext_vector_type(8)));
typedef float f32x4_t __attribute__((ext_vector_type(4)));

static __device__ __forceinline__ float b2f(unsigned short h) {
    unsigned u = ((unsigned)h) << 16;
    return __builtin_bit_cast(float, u);
}
static __device__ __forceinline__ unsigned short f2b(float f) {
    unsigned u = __builtin_bit_cast(unsigned, f);
    u += 0x7FFFu + ((u >> 16) & 1u);   // RNE; values finite O(1)
    return (unsigned short)(u >> 16);
}

// ---------------- merged prep: f32->bf16 shadow of h  +  weight repack ----------------
// blocks [0,3125): to_bf16 of h (3125*256*8 = 6.4M exact)
// blocks [3125,3301): repack w0/w1/w2/wp into MFMA fragment order
// frag offset for (k,n): nt=n>>4,m=n&15,kt=k>>5,quad=(k>>3)&3,j=k&7
//   off = ((nt*4+kt)*64 + quad*16 + m)*8 + j   -> lane L=quad*16+m reads chunk L contiguous
__global__ __launch_bounds__(256) void prep(const float* __restrict__ hsrc,
                                            unsigned short* __restrict__ hout,
                                            const float* __restrict__ w0,
                                            const float* __restrict__ w1,
                                            const float* __restrict__ w2,
                                            const float* __restrict__ wp,
                                            unsigned short* __restrict__ f0h,
                                            unsigned short* __restrict__ f0l,
                                            unsigned short* __restrict__ f1h,
                                            unsigned short* __restrict__ f1l,
                                            unsigned short* __restrict__ f2h,
                                            unsigned short* __restrict__ f2l,
                                            unsigned short* __restrict__ fph,
                                            unsigned short* __restrict__ fpl) {
    if (blockIdx.x < 3125) {
        size_t e0 = ((size_t)blockIdx.x * 256 + threadIdx.x) * 8;
        f32x4_t v0 = *(const f32x4_t*)(hsrc + e0);
        f32x4_t v1 = *(const f32x4_t*)(hsrc + e0 + 4);
        us8_t o;
        #pragma unroll
        for (int j = 0; j < 4; ++j) { o[j] = f2b(v0[j]); o[4 + j] = f2b(v1[j]); }
        *(us8_t*)(hout + e0) = o;
        return;
    }
    int t = (blockIdx.x - 3125) * 256 + threadIdx.x;
    const float* src;
    unsigned short *dh, *dl;
    int idx, ncols;
    if (t < 16384)      { src = w0; dh = f0h; dl = f0l; idx = t;         ncols = 128; }
    else if (t < 32768) { src = w1; dh = f1h; dl = f1l; idx = t - 16384; ncols = 128; }
    else if (t < 38912) { src = w2; dh = f2h; dl = f2l; idx = t - 32768; ncols = 48; }
    else if (t < 45056) { src = wp; dh = fph; dl = fpl; idx = t - 38912; ncols = 48; }
    else return;
    int k = idx / ncols, n = idx - k * ncols;
    float v;
    if (ncols == 128) v = src[k * 128 + n];
    else              v = (n < NCLS) ? src[k * NCLS + n] : 0.f;
    int nt = n >> 4, m = n & 15, kt = k >> 5, quad = (k >> 3) & 3, j = k & 7;
    int off = ((nt * 4 + kt) * 64 + quad * 16 + m) * 8 + j;
    unsigned short hi = f2b(v);
    dh[off] = hi;
    dl[off] = f2b(v - b2f(hi));
}

// ---------------- per-chunk per-node edge counts (LDS atomics); blockIdx.y = half ----------------
__global__ __launch_bounds__(256) void chunk_count(const int* __restrict__ dst,
                                                   unsigned* __restrict__ cnt) {
    __shared__ unsigned lds[WHALF];   // 50 KB
    int c = blockIdx.x, h = blockIdx.y, tid = threadIdx.x;
    for (int w = tid; w < WHALF; w += 256) lds[w] = 0;
    __syncthreads();
    int base = c * CE;
    for (int k = tid; k < CE; k += 256) {
        int local = dst[base + k] - h * HALF_N;
        if (local >= 0 && local < HALF_N)
            atomicAdd(&lds[local >> 1], 1u << ((local & 1) * 16));
    }
    __syncthreads();
    unsigned* out = cnt + ((size_t)(h * NCHUNK + c)) * WHALF;
    for (int w = tid; w < WHALF; w += 256) out[w] = lds[w];
}

// ---------------- scan over chunk axis ----------------
__global__ __launch_bounds__(256) void cscan(unsigned* __restrict__ cnt,
                                             unsigned* __restrict__ degp,
                                             int* __restrict__ partial) {
    __shared__ int lds[256];
    int b = blockIdx.x;
    int h = b / 49;
    int w = (b % 49) * 256 + threadIdx.x;
    unsigned acc = 0;
    for (int c = 0; c < NCHUNK; ++c) {
        size_t idx = ((size_t)(h * NCHUNK + c)) * WHALF + w;
        unsigned v = cnt[idx];
        cnt[idx] = acc;          // exclusive prefix (packed halves)
        acc += v;
    }
    degp[h * WHALF + w] = acc;
    lds[threadIdx.x] = (int)(acc & 0xFFFFu) + (int)(acc >> 16);
    __syncthreads();
    #pragma unroll
    for (int off = 128; off > 0; off >>= 1) {
        if (threadIdx.x < off) lds[threadIdx.x] += lds[threadIdx.x + off];
        __syncthreads();
    }
    if (threadIdx.x == 0) partial[b] = lds[0];
}

// ---------------- final node-axis scan (scan_blocks folded in): rs / deg / dinv ----------------
__global__ __launch_bounds__(256) void scan_final(const unsigned* __restrict__ degp,
                                                  const int* __restrict__ partial,
                                                  int* __restrict__ rs,
                                                  int* __restrict__ deg,
                                                  float* __restrict__ dinv) {
    __shared__ int lds[256];
    int b = blockIdx.x;
    int h = b / 49;
    int tid = threadIdx.x;
    int w = (b % 49) * 256 + tid;
    // block offset = sum of partial[j], j < b  (block-wide reduction; b < SCAN_B <= 256)
    lds[tid] = (tid < b) ? partial[tid] : 0;
    __syncthreads();
    #pragma unroll
    for (int off = 128; off > 0; off >>= 1) {
        if (tid < off) lds[tid] += lds[tid + off];
        __syncthreads();
    }
    int boff = lds[0];
    __syncthreads();
    unsigned dp = degp[h * WHALF + w];
    int lo = (int)(dp & 0xFFFFu), hi = (int)(dp >> 16);
    int s = lo + hi;
    lds[tid] = s;
    __syncthreads();
    #pragma unroll
    for (int off = 1; off < 256; off <<= 1) {
        int v = lds[tid];
        int add = (tid >= off) ? lds[tid - off] : 0;
        __syncthreads();
        lds[tid] = v + add;
        __syncthreads();
    }
    int excl = boff + lds[tid] - s;
    int n0 = h * HALF_N + 2 * w;
    rs[n0] = excl;
    rs[n0 + 1] = excl + lo;
    deg[n0] = lo;
    deg[n0 + 1] = hi;
    dinv[n0] = (lo > 0) ? (1.0f / (float)lo) : 0.0f;
    dinv[n0 + 1] = (hi > 0) ? (1.0f / (float)hi) : 0.0f;
}

// ---------------- CSR fill: rank via LDS returning atomics; blockIdx.y = half ----------------
__global__ __launch_bounds__(256) void fill2(const int* __restrict__ src,
                                             const int* __restrict__ dst,
                                             const float* __restrict__ mask,
                                             const unsigned* __restrict__ cnt,
                                             const int* __restrict__ rs,
                                             unsigned* __restrict__ csr) {
    __shared__ unsigned cur[WHALF];   // 50 KB
    int c = blockIdx.x, h = blockIdx.y, tid = threadIdx.x;
    const unsigned* off = cnt + ((size_t)(h * NCHUNK + c)) * WHALF;
    for (int w = tid; w < WHALF; w += 256) cur[w] = off[w];
    __syncthreads();
    int base = c * CE;
    for (int k = tid; k < CE; k += 256) {
        int e = base + k;
        int d = dst[e];
        int local = d - h * HALF_N;
        if (local >= 0 && local < HALF_N) {
            unsigned sm = (unsigned)src[e] | ((unsigned)f2b(mask[e]) << 16);
            int sh = (local & 1) * 16;
            unsigned old = atomicAdd(&cur[local >> 1], 1u << sh);
            int rank = (int)((old >> sh) & 0xFFFFu);
            csr[rs[d] + rank] = sm;
        }
    }
}

// ---------------- one node per wave: gather (x + mean-agg) row into LDS ----------------
// Lane owns dims lane*2, lane*2+1. Avg degree 16 => ~1 chunk: short critical path;
// latency hidden by 32 waves/CU TLP, not in-wave ILP.
static __device__ __forceinline__ void gather1(const unsigned short* __restrict__ xb,
                                               const float* __restrict__ xres,
                                               const int* __restrict__ rs,
                                               const int* __restrict__ deg,
                                               const float* __restrict__ dinv,
                                               const unsigned* __restrict__ csr,
                                               int node, int lane,
                                               float (*ldsrow)[132], int row) {
    int start = rs[node], dg = deg[node];
    float di = dinv[node];
    float acc0 = 0.f, acc1 = 0.f;
    for (int base = 0; base < dg; base += 16) {
        int nb = dg - base;
        if (nb > 16) nb = 16;
        unsigned pk = (lane < nb) ? csr[start + base + lane] : 0u;
        unsigned vv[16];
        #pragma unroll
        for (int j = 0; j < 16; ++j) {
            unsigned p = (unsigned)__builtin_amdgcn_readlane((int)pk, j);  // 0 for j>=nb
            vv[j] = *(const unsigned*)(xb + (size_t)(p & 0xFFFFu) * DIM + lane * 2);
        }
        #pragma unroll
        for (int j = 0; j < 16; ++j) {
            unsigned p = (unsigned)__builtin_amdgcn_readlane((int)pk, j);
            float mm = b2f((unsigned short)(p >> 16));                     // 0 for j>=nb
            acc0 += mm * b2f((unsigned short)(vv[j] & 0xFFFFu));
            acc1 += mm * b2f((unsigned short)(vv[j] >> 16));
        }
    }
    float2 xp = *(const float2*)(xres + (size_t)node * DIM + lane * 2);
    ldsrow[row][lane * 2]     = xp.x + acc0 * di;
    ldsrow[row][lane * 2 + 1] = xp.y + acc1 * di;
}

// ---------------- fused agg + GEMM[N,128]x[128,128] + BN + ReLU ----------------
// 1024-thread blocks, 16 waves = 16 rows, ONE node per wave (50000 gather waves).
// Phase 2: waves 0..7 each own one 16-col tile; waves 8..15 exit.
__global__ __launch_bounds__(1024, 8) void fused_layer(const unsigned short* __restrict__ xb,
                                                       const float* __restrict__ x,
                                                       const int* __restrict__ rs,
                                                       const int* __restrict__ deg,
                                                       const float* __restrict__ dinv,
                                                       const unsigned* __restrict__ csr,
                                                       const unsigned short* __restrict__ wfh,
                                                       const unsigned short* __restrict__ wfl,
                                                       const float* __restrict__ bias,
                                                       const float* __restrict__ gam,
                                                       const float* __restrict__ bet,
                                                       const float* __restrict__ rm,
                                                       const float* __restrict__ rv,
                                                       float* __restrict__ out,
                                                       unsigned short* __restrict__ outb) {
    __shared__ float lds[16][132];   // 8.4 KB
    int tid = threadIdx.x;
    int wave = tid >> 6, lane = tid & 63;
    int rbase = blockIdx.x * 16;     // 3125 * 16 == 50000 exactly, no bounds checks

    // ---- phase 1: this wave aggregates exactly one node ----
    gather1(xb, x, rs, deg, dinv, csr, rbase + wave, lane, lds, wave);
    __syncthreads();   // cross-lane LDS dependency: barrier REQUIRED

    if (wave >= 8) return;   // no further barriers: early exit is legal

    // ---- phase 2: 16x128 GEMM, col-tile nt = wave ----
    int m = lane & 15, quad = lane >> 4;
    const float* ap = &lds[m][0];

    us8_t ah[4], al[4];
    #pragma unroll
    for (int kt = 0; kt < 4; ++kt) {
        f32x4_t p0 = *(const f32x4_t*)(ap + kt * 32 + quad * 8);
        f32x4_t p1 = *(const f32x4_t*)(ap + kt * 32 + quad * 8 + 4);
        #pragma unroll
        for (int j = 0; j < 4; ++j) {
            unsigned short h0 = f2b(p0[j]);
            unsigned short h1 = f2b(p1[j]);
            ah[kt][j] = h0;
            ah[kt][4 + j] = h1;
            al[kt][j] = f2b(p0[j] - b2f(h0));
            al[kt][4 + j] = f2b(p1[j] - b2f(h1));
        }
    }

    int nt = wave;
    f32x4_t acc = {};
    #pragma unroll
    for (int kt = 0; kt < 4; ++kt) {
        int boff = ((nt * 4 + kt) * 64 + lane) * 8;
        us8_t bh = *(const us8_t*)(wfh + boff);
        us8_t bl = *(const us8_t*)(wfl + boff);
        acc = __builtin_amdgcn_mfma_f32_16x16x32_bf16(
            __builtin_bit_cast(bf16x8_t, ah[kt]),
            __builtin_bit_cast(bf16x8_t, bh), acc, 0, 0, 0);
        acc = __builtin_amdgcn_mfma_f32_16x16x32_bf16(
            __builtin_bit_cast(bf16x8_t, ah[kt]),
            __builtin_bit_cast(bf16x8_t, bl), acc, 0, 0, 0);
        acc = __builtin_amdgcn_mfma_f32_16x16x32_bf16(
            __builtin_bit_cast(bf16x8_t, al[kt]),
            __builtin_bit_cast(bf16x8_t, bh), acc, 0, 0, 0);
    }

    int j = nt * 16 + m;
    float bj = bias[j];
    float sc = gam[j] * rsqrtf(rv[j] + 1e-5f);
    float sh = bet[j] - rm[j] * sc;
    #pragma unroll
    for (int i = 0; i < 4; ++i) {
        int r = rbase + quad * 4 + i;
        float z = fmaxf((acc[i] + bj) * sc + sh, 0.f);
        out[(size_t)r * DIM + j] = z;
        outb[(size_t)r * DIM + j] = f2b(z);
    }
}

// ---------------- fused final: agg + h3 = relu(BN((h2+agg)@w2+b2)); out = (h2@wp+bp+h3)*0.5 ----------------
// 1024-thread blocks, one node per wave. Phase 2 split to keep VGPR <= 64:
// waves 0..2: h3 path (A from LDS) | waves 3..5: predict path (A from h2 global),
// accp handed over via 3 KB LDS buffer; one extra barrier; waves 0..2 combine.
__global__ __launch_bounds__(1024, 8) void fused_final2(const unsigned short* __restrict__ xb,
                                                        const float* __restrict__ h2,
                                                        const int* __restrict__ rs,
                                                        const int* __restrict__ deg,
                                                        const float* __restrict__ dinv,
                                                        const unsigned* __restrict__ csr,
                                                        const unsigned short* __restrict__ f2h,
                                                        const unsigned short* __restrict__ f2l,
                                                        const unsigned short* __restrict__ fph,
                                                        const unsigned short* __restrict__ fpl,
                                                        const float* __restrict__ b2,
                                                        const float* __restrict__ g2,
                                                        const float* __restrict__ be2,
                                                        const float* __restrict__ rm2,
                                                        const float* __restrict__ rv2,
                                                        const float* __restrict__ bp,
                                                        float* __restrict__ out) {
    __shared__ float lds[16][132];
    __shared__ float pbuf[3][16][16];   // predict-path accumulators
    int tid = threadIdx.x;
    int wave = tid >> 6, lane = tid & 63;
    int rbase = blockIdx.x * 16;

    // ---- phase 1 ----
    gather1(xb, h2, rs, deg, dinv, csr, rbase + wave, lane, lds, wave);
    __syncthreads();

    int m = lane & 15, quad = lane >> 4;
    f32x4_t myacc = {};

    if (wave >= 3 && wave < 6) {
        // ---- predict path: accp = h2 @ wp (A-fragments from global h2, L2-hot) ----
        int nt = wave - 3;
        const float* aph = h2 + (size_t)(rbase + m) * DIM;
        us8_t hh[4], hl[4];
        #pragma unroll
        for (int kt = 0; kt < 4; ++kt) {
            f32x4_t q0 = *(const f32x4_t*)(aph + kt * 32 + quad * 8);
            f32x4_t q1 = *(const f32x4_t*)(aph + kt * 32 + quad * 8 + 4);
            #pragma unroll
            for (int j = 0; j < 4; ++j) {
                unsigned short g0 = f2b(q0[j]), g1 = f2b(q1[j]);
                hh[kt][j] = g0; hh[kt][4 + j] = g1;
                hl[kt][j] = f2b(q0[j] - b2f(g0));
                hl[kt][4 + j] = f2b(q1[j] - b2f(g1));
            }
        }
        #pragma unroll
        for (int kt = 0; kt < 4; ++kt) {
            int boff = ((nt * 4 + kt) * 64 + lane) * 8;
            us8_t bphv = *(const us8_t*)(fph + boff);
            us8_t bplv = *(const us8_t*)(fpl + boff);
            myacc = __builtin_amdgcn_mfma_f32_16x16x32_bf16(
                __builtin_bit_cast(bf16x8_t, hh[kt]),
                __builtin_bit_cast(bf16x8_t, bphv), myacc, 0, 0, 0);
            myacc = __builtin_amdgcn_mfma_f32_16x16x32_bf16(
                __builtin_bit_cast(bf16x8_t, hh[kt]),
                __builtin_bit_cast(bf16x8_t, bplv), myacc, 0, 0, 0);
            myacc = __builtin_amdgcn_mfma_f32_16x16x32_bf16(
                __builtin_bit_cast(bf16x8_t, hl[kt]),
                __builtin_bit_cast(bf16x8_t, bphv), myacc, 0, 0, 0);
        }
        #pragma unroll
        for (int i = 0; i < 4; ++i)
            pbuf[nt][quad * 4 + i][m] = myacc[i];
    } else if (wave < 3) {
        // ---- h3 path: acc2 = (h2+agg) @ w2 (A-fragments from LDS) ----
        int nt = wave;
        const float* ap2 = &lds[m][0];
        us8_t a2h[4], a2l[4];
        #pragma unroll
        for (int kt = 0; kt < 4; ++kt) {
            f32x4_t p0 = *(const f32x4_t*)(ap2 + kt * 32 + quad * 8);
            f32x4_t p1 = *(const f32x4_t*)(ap2 + kt * 32 + quad * 8 + 4);
            #pragma unroll
            for (int j = 0; j < 4; ++j) {
                unsigned short h0 = f2b(p0[j]), h1 = f2b(p1[j]);
                a2h[kt][j] = h0; a2h[kt][4 + j] = h1;
                a2l[kt][j] = f2b(p0[j] - b2f(h0));
                a2l[kt][4 + j] = f2b(p1[j] - b2f(h1));
            }
        }
        #pragma unroll
        for (int kt = 0; kt < 4; ++kt) {
            int boff = ((nt * 4 + kt) * 64 + lane) * 8;
            us8_t b2hv = *(const us8_t*)(f2h + boff);
            us8_t b2lv = *(const us8_t*)(f2l + boff);
            myacc = __builtin_amdgcn_mfma_f32_16x16x32_bf16(
                __builtin_bit_cast(bf16x8_t, a2h[kt]),
                __builtin_bit_cast(bf16x8_t, b2hv), myacc, 0, 0, 0);
            myacc = __builtin_amdgcn_mfma_f32_16x16x32_bf16(
                __builtin_bit_cast(bf16x8_t, a2h[kt]),
                __builtin_bit_cast(bf16x8_t, b2lv), myacc, 0, 0, 0);
            myacc = __builtin_amdgcn_mfma_f32_16x16x32_bf16(
                __builtin_bit_cast(bf16x8_t, a2l[kt]),
                __builtin_bit_cast(bf16x8_t, b2hv), myacc, 0, 0, 0);
        }
    }
    __syncthreads();   // pbuf ready

    if (wave < 3) {
        int nt = wave;
        int j = nt * 16 + m;
        if (j < NCLS) {
            float b2j = b2[j];
            float sc = g2[j] * rsqrtf(rv2[j] + 1e-5f);
            float sh = be2[j] - rm2[j] * sc;
            float bpj = bp[j];
            #pragma unroll
            for (int i = 0; i < 4; ++i) {
                int r = rbase + quad * 4 + i;
                float z = fmaxf((myacc[i] + b2j) * sc + sh, 0.f);
                float p = pbuf[nt][quad * 4 + i][m] + bpj;
                out[(size_t)r * NCLS + j] = (p + z) * 0.5f;
            }
        }
    }
}

extern "C" void kernel_launch(void* const* d_in, const int* in_sizes, int n_in,
                              void* d_out, int out_size, void* d_ws, size_t ws_size,
                              hipStream_t stream) {
    const float* h    = (const float*)d_in[0];
    const int* esrc   = (const int*)d_in[1];
    const int* edst   = (const int*)d_in[2];
    const float* mask = (const float*)d_in[3];
    const float* w0   = (const float*)d_in[4];
    const float* b0   = (const float*)d_in[5];
    const float* g0   = (const float*)d_in[6];
    const float* be0  = (const float*)d_in[7];
    const float* rm0  = (const float*)d_in[8];
    const float* rv0  = (const float*)d_in[9];
    const float* w1   = (const float*)d_in[10];
    const float* b1   = (const float*)d_in[11];
    const float* g1   = (const float*)d_in[12];
    const float* be1  = (const float*)d_in[13];
    const float* rm1  = (const float*)d_in[14];
    const float* rv1  = (const float*)d_in[15];
    const float* w2   = (const float*)d_in[16];
    const float* b2   = (const float*)d_in[17];
    const float* g2   = (const float*)d_in[18];
    const float* be2  = (const float*)d_in[19];
    const float* rm2  = (const float*)d_in[20];
    const float* rv2  = (const float*)d_in[21];
    const float* wp   = (const float*)d_in[22];
    const float* bp   = (const float*)d_in[23];

    char* ws = (char*)d_ws;
    size_t off = 0;
    auto alloc = [&](size_t bytes) {
        char* p = ws + off;
        off = (off + bytes + 255) & ~(size_t)255;
        return p;
    };
    int* rs       = (int*)alloc(N_PAD * 4);
    int* deg      = (int*)alloc(N_PAD * 4);
    float* dinv   = (float*)alloc(N_PAD * 4);
    int* partial  = (int*)alloc(128 * 4);
    unsigned* degp = (unsigned*)alloc(2 * WHALF * 4);
    unsigned* csr = (unsigned*)alloc((size_t)N_EDGES * 4);
    unsigned* cnt = (unsigned*)alloc((size_t)2 * NCHUNK * WHALF * 4);  // 12.85 MB
    float* hbA    = (float*)alloc((size_t)N_NODES * DIM * 4);
    float* hbB    = (float*)alloc((size_t)N_NODES * DIM * 4);
    unsigned short* xb16  = (unsigned short*)alloc((size_t)N_NODES * DIM * 2);
    unsigned short* hbA16 = (unsigned short*)alloc((size_t)N_NODES * DIM * 2);
    unsigned short* hbB16 = (unsigned short*)alloc((size_t)N_NODES * DIM * 2);
    unsigned short* f0h = (unsigned short*)alloc(16384 * 2);
    unsigned short* f0l = (unsigned short*)alloc(16384 * 2);
    unsigned short* f1h = (unsigned short*)alloc(16384 * 2);
    unsigned short* f1l = (unsigned short*)alloc(16384 * 2);
    unsigned short* f2h = (unsigned short*)alloc(6144 * 2);
    unsigned short* f2l = (unsigned short*)alloc(6144 * 2);
    unsigned short* fph = (unsigned short*)alloc(6144 * 2);
    unsigned short* fpl = (unsigned short*)alloc(6144 * 2);

    const int GB16 = N_NODES / 16;   // 3125, exact

    prep<<<3301, 256, 0, stream>>>(h, xb16, w0, w1, w2, wp,
                                   f0h, f0l, f1h, f1l, f2h, f2l, fph, fpl);
    chunk_count<<<dim3(NCHUNK, 2), 256, 0, stream>>>(edst, cnt);
    cscan<<<SCAN_B, 256, 0, stream>>>(cnt, degp, partial);
    scan_final<<<SCAN_B, 256, 0, stream>>>(degp, partial, rs, deg, dinv);
    fill2<<<dim3(NCHUNK, 2), 256, 0, stream>>>(esrc, edst, mask, cnt, rs, csr);

    // layer 0: reads (h, xb16) -> writes (hbA, hbA16)
    fused_layer<<<GB16, 1024, 0, stream>>>(xb16, h, rs, deg, dinv, csr,
                                           f0h, f0l, b0, g0, be0, rm0, rv0, hbA, hbA16);
    // layer 1: reads (hbA, hbA16) -> writes (hbB, hbB16)  (double-buffered)
    fused_layer<<<GB16, 1024, 0, stream>>>(hbA16, hbA, rs, deg, dinv, csr,
                                           f1h, f1l, b1, g1, be1, rm1, rv1, hbB, hbB16);
    // layer 2 + predict, fused: reads (hbB, hbB16) -> d_out
    fused_final2<<<GB16, 1024, 0, stream>>>(hbB16, hbB, rs, deg, dinv, csr,
                                            f2h, f2l, fph, fpl,
                                            b2, g2, be2, rm2, rv2, bp, (float*)d_out);
}